// Round 5
// baseline (30.182 us; speedup 1.0000x reference)
//
#include <hip/hip_runtime.h>

#define B 4
#define NQ 512
#define NK 512
#define D 128
#define H 32
#define G 4                              // queries per context block
#define PS 2.8853900817779268f           // 2*log2(e)

__device__ __forceinline__ float rcp_f(float x)  { return __builtin_amdgcn_rcpf(x); }
__device__ __forceinline__ float exp2_f(float x) { return __builtin_amdgcn_exp2f(x); }

__device__ __forceinline__ void fma4(float4& a, const float4& v, float s) {
    a.x = fmaf(s, v.x, a.x);
    a.y = fmaf(s, v.y, a.y);
    a.z = fmaf(s, v.z, a.z);
    a.w = fmaf(s, v.w, a.w);
}

// kh_t[b][h][k] = PS*(keys[b,k,:].Wk[:,h] + b1[h]),  qh[b][q][h] = PS*(queries[b,q,:].Wq[:,h])
__global__ __launch_bounds__(256) void proj_kernel(
    const float* __restrict__ keys, const float* __restrict__ queries,
    const float* __restrict__ Wk, const float* __restrict__ Wq,
    const float* __restrict__ b1,
    float* __restrict__ kh_t, float* __restrict__ qh)
{
    __shared__ float xs[8][D];
    const int tid = threadIdx.x;
    const int r0 = blockIdx.x * 8;
    const bool is_q = (r0 >= B * NK);
    const float* __restrict__ X = is_q ? (queries + (size_t)(r0 - B * NK) * D)
                                       : (keys + (size_t)r0 * D);
    const float* __restrict__ W = is_q ? Wq : Wk;

    reinterpret_cast<float4*>(&xs[0][0])[tid] =
        reinterpret_cast<const float4*>(X)[tid];
    __syncthreads();

    const int lr = tid >> 5;
    const int h  = tid & 31;
    float a0 = 0.f, a1 = 0.f, a2 = 0.f, a3 = 0.f;
    const float4* x4 = reinterpret_cast<const float4*>(&xs[lr][0]);
    #pragma unroll
    for (int i = 0; i < D / 4; ++i) {
        float4 v = x4[i];
        a0 = fmaf(v.x, W[(4 * i + 0) * H + h], a0);
        a1 = fmaf(v.y, W[(4 * i + 1) * H + h], a1);
        a2 = fmaf(v.z, W[(4 * i + 2) * H + h], a2);
        a3 = fmaf(v.w, W[(4 * i + 3) * H + h], a3);
    }
    float acc = (a0 + a1) + (a2 + a3);
    if (is_q) {
        const int rq = r0 - B * NK + lr;
        qh[(size_t)rq * H + h] = acc * PS;
    } else {
        const int r = r0 + lr;
        const int b = r >> 9;
        const int k = r & (NK - 1);
        kh_t[((size_t)b * H + h) * NK + k] = (acc + b1[h]) * PS;
    }
}

// 2 queries per block, 1024 blocks, 256 threads. Thread owns k-pair (2t, 2t+1).
// Writes normalized softmax weights ex[b][q][k].
__global__ __launch_bounds__(256) void score_kernel(
    const float* __restrict__ kh_t,   // [B][H][NK], pre-scaled
    const float* __restrict__ qh,     // [B][NQ][H], pre-scaled
    const float* __restrict__ w2,
    float* __restrict__ ex)           // [B][NQ][NK]
{
    __shared__ float qv_s[2][H];
    __shared__ float w2_s[H];
    __shared__ float redm[2][4];
    __shared__ float reds[2][4];

    const int tid = threadIdx.x;
    const int w   = tid >> 6;
    const int b   = blockIdx.x >> 8;          // 256 blocks per batch
    const int q0  = (blockIdx.x & 255) * 2;

    if (tid < H)            w2_s[tid] = -PS * w2[tid];
    else if (tid < 2 * H)   qv_s[0][tid - H]     = qh[((size_t)b * NQ + q0) * H + (tid - H)];
    else if (tid < 3 * H)   qv_s[1][tid - 2 * H] = qh[((size_t)b * NQ + q0 + 1) * H + (tid - 2 * H)];
    __syncthreads();

    const float* khb = kh_t + (size_t)b * H * NK;
    float l00 = 0.f, l01 = 0.f, l10 = 0.f, l11 = 0.f;   // [q][k] chains
    #pragma unroll 8
    for (int h = 0; h < H; ++h) {
        const float2 kv = *reinterpret_cast<const float2*>(khb + h * NK + 2 * tid);
        const float qv0 = qv_s[0][h];         // LDS broadcasts
        const float qv1 = qv_s[1][h];
        const float wp  = w2_s[h];
        l00 = fmaf(wp, rcp_f(1.f + exp2_f(qv0 + kv.x)), l00);
        l01 = fmaf(wp, rcp_f(1.f + exp2_f(qv0 + kv.y)), l01);
        l10 = fmaf(wp, rcp_f(1.f + exp2_f(qv1 + kv.x)), l10);
        l11 = fmaf(wp, rcp_f(1.f + exp2_f(qv1 + kv.y)), l11);
    }

    // block softmax for both queries
    float m0 = fmaxf(l00, l01), m1 = fmaxf(l10, l11);
    #pragma unroll
    for (int off = 32; off; off >>= 1) {
        m0 = fmaxf(m0, __shfl_xor(m0, off));
        m1 = fmaxf(m1, __shfl_xor(m1, off));
    }
    if ((tid & 63) == 0) { redm[0][w] = m0; redm[1][w] = m1; }
    __syncthreads();
    m0 = fmaxf(fmaxf(redm[0][0], redm[0][1]), fmaxf(redm[0][2], redm[0][3]));
    m1 = fmaxf(fmaxf(redm[1][0], redm[1][1]), fmaxf(redm[1][2], redm[1][3]));

    const float e00 = exp2_f(l00 - m0), e01 = exp2_f(l01 - m0);
    const float e10 = exp2_f(l10 - m1), e11 = exp2_f(l11 - m1);
    float s0 = e00 + e01, s1 = e10 + e11;
    #pragma unroll
    for (int off = 32; off; off >>= 1) {
        s0 += __shfl_xor(s0, off);
        s1 += __shfl_xor(s1, off);
    }
    if ((tid & 63) == 0) { reds[0][w] = s0; reds[1][w] = s1; }
    __syncthreads();
    s0 = (reds[0][0] + reds[0][1]) + (reds[0][2] + reds[0][3]);
    s1 = (reds[1][0] + reds[1][1]) + (reds[1][2] + reds[1][3]);
    const float inv0 = 1.f / s0, inv1 = 1.f / s1;

    const float2 o0 = { e00 * inv0, e01 * inv0 };
    const float2 o1 = { e10 * inv1, e11 * inv1 };
    reinterpret_cast<float2*>(ex + ((size_t)b * NQ + q0) * NK)[tid]     = o0;
    reinterpret_cast<float2*>(ex + ((size_t)b * NQ + q0 + 1) * NK)[tid] = o1;
}

// G=4 queries per block, 512 blocks, 512 threads = 8 waves (16 k-partitions x 32 d-groups).
__global__ __launch_bounds__(512) void context_kernel(
    const float* __restrict__ keys,
    const float* __restrict__ ex,     // [B][NQ][NK] normalized weights
    float* __restrict__ outp)
{
    __shared__ float acc_s[16][G][D];   // 32 KB

    const int tid = threadIdx.x;
    const int dg  = tid & 31;           // d-group: 4 floats each
    const int kp  = tid >> 5;           // 0..15, 32 keys each
    const int b   = blockIdx.x >> 7;
    const int q0  = (blockIdx.x & 127) * G;

    const float4* k4 = reinterpret_cast<const float4*>(
        keys + ((size_t)b * NK + kp * 32) * D) + dg;
    const float* exb = ex + ((size_t)b * NQ + q0) * NK + kp * 32;

    float4 a0 = {0,0,0,0}, a1 = a0, a2 = a0, a3 = a0;
    #pragma unroll 2
    for (int kk4 = 0; kk4 < 8; ++kk4) {
        float ev0[4], ev1[4], ev2[4], ev3[4];
        *reinterpret_cast<float4*>(ev0) = reinterpret_cast<const float4*>(exb)[kk4];
        *reinterpret_cast<float4*>(ev1) = reinterpret_cast<const float4*>(exb + NK)[kk4];
        *reinterpret_cast<float4*>(ev2) = reinterpret_cast<const float4*>(exb + 2 * NK)[kk4];
        *reinterpret_cast<float4*>(ev3) = reinterpret_cast<const float4*>(exb + 3 * NK)[kk4];
        #pragma unroll
        for (int j = 0; j < 4; ++j) {
            float4 kv = k4[(size_t)(4 * kk4 + j) * (D / 4)];
            fma4(a0, kv, ev0[j]);
            fma4(a1, kv, ev1[j]);
            fma4(a2, kv, ev2[j]);
            fma4(a3, kv, ev3[j]);
        }
    }
    *reinterpret_cast<float4*>(&acc_s[kp][0][4 * dg]) = a0;
    *reinterpret_cast<float4*>(&acc_s[kp][1][4 * dg]) = a1;
    *reinterpret_cast<float4*>(&acc_s[kp][2][4 * dg]) = a2;
    *reinterpret_cast<float4*>(&acc_s[kp][3][4 * dg]) = a3;
    __syncthreads();

    // 512 threads -> 512 outputs (g,d)
    const int g = tid >> 7;
    const int d = tid & 127;
    float r = 0.f;
    #pragma unroll
    for (int p = 0; p < 16; ++p) r += acc_s[p][g][d];
    outp[((size_t)b * NQ + q0 + g) * D + d] = r;
}

extern "C" void kernel_launch(void* const* d_in, const int* in_sizes, int n_in,
                              void* d_out, int out_size, void* d_ws, size_t ws_size,
                              hipStream_t stream) {
    const float* keys    = (const float*)d_in[0];
    const float* queries = (const float*)d_in[1];
    const float* Wk      = (const float*)d_in[2];
    const float* Wq      = (const float*)d_in[3];
    const float* b1      = (const float*)d_in[4];
    const float* w2      = (const float*)d_in[5];
    // d_in[6] = b2: dropped (softmax shift-invariant)
    float* out = (float*)d_out;

    float* kh_t = (float*)d_ws;                    // B*H*NK
    float* qh   = kh_t + (size_t)B * H * NK;       // B*NQ*H
    float* exw  = qh + (size_t)B * NQ * H;         // B*NQ*NK (4 MB)

    proj_kernel<<<(B * NK + B * NQ) / 8, 256, 0, stream>>>(keys, queries, Wk, Wq, b1, kh_t, qh);
    score_kernel<<<B * NQ / 2, 256, 0, stream>>>(kh_t, qh, w2, exw);
    context_kernel<<<B * NQ / G, 512, 0, stream>>>(keys, exw, out);
}

// Round 6
// 21.389 us; speedup vs baseline: 1.4111x; 1.4111x over previous
//
#include <hip/hip_runtime.h>

#define B 4
#define NQ 512
#define NK 512
#define D 128
#define H 32
#define G 4                              // queries per attend block
#define PS 2.8853900817779268f           // 2*log2(e)

__device__ __forceinline__ float rcp_f(float x)  { return __builtin_amdgcn_rcpf(x); }
__device__ __forceinline__ float exp2_f(float x) { return __builtin_amdgcn_exp2f(x); }

__device__ __forceinline__ void fma4(float4& a, const float4& v, float s) {
    a.x = fmaf(s, v.x, a.x);
    a.y = fmaf(s, v.y, a.y);
    a.z = fmaf(s, v.z, a.z);
    a.w = fmaf(s, v.w, a.w);
}

// Ek[b][h][k] = exp2(PS*(keys[b,k,:].Wk[:,h] + b1[h]))   (transposed)
// eq[b][q][h] = exp2(PS*(queries[b,q,:].Wq[:,h]))
// Then exp2(PS*(qh+kh)) = eq*Ek, so attend needs only ONE trans (rcp) per element.
__global__ __launch_bounds__(256) void proj_kernel(
    const float* __restrict__ keys, const float* __restrict__ queries,
    const float* __restrict__ Wk, const float* __restrict__ Wq,
    const float* __restrict__ b1,
    float* __restrict__ Ek, float* __restrict__ eq)
{
    __shared__ float xs[8][D];
    const int tid = threadIdx.x;
    const int r0 = blockIdx.x * 8;
    const bool is_q = (r0 >= B * NK);
    const float* __restrict__ X = is_q ? (queries + (size_t)(r0 - B * NK) * D)
                                       : (keys + (size_t)r0 * D);
    const float* __restrict__ W = is_q ? Wq : Wk;

    reinterpret_cast<float4*>(&xs[0][0])[tid] =
        reinterpret_cast<const float4*>(X)[tid];
    __syncthreads();

    const int lr = tid >> 5;
    const int h  = tid & 31;
    float a0 = 0.f, a1 = 0.f, a2 = 0.f, a3 = 0.f;
    const float4* x4 = reinterpret_cast<const float4*>(&xs[lr][0]);
    #pragma unroll
    for (int i = 0; i < D / 4; ++i) {
        float4 v = x4[i];
        a0 = fmaf(v.x, W[(4 * i + 0) * H + h], a0);
        a1 = fmaf(v.y, W[(4 * i + 1) * H + h], a1);
        a2 = fmaf(v.z, W[(4 * i + 2) * H + h], a2);
        a3 = fmaf(v.w, W[(4 * i + 3) * H + h], a3);
    }
    float acc = (a0 + a1) + (a2 + a3);
    if (is_q) {
        const int rq = r0 - B * NK + lr;
        eq[(size_t)rq * H + h] = exp2_f(acc * PS);
    } else {
        const int r = r0 + lr;
        const int b = r >> 9;
        const int k = r & (NK - 1);
        Ek[((size_t)b * H + h) * NK + k] = exp2_f((acc + b1[h]) * PS);
    }
}

// One block per (b, group of G=4 queries). 256 threads = 4 waves, wave w owns query q0+w.
__global__ __launch_bounds__(256) void attend_kernel(
    const float* __restrict__ keys,
    const float* __restrict__ Ek,     // [B][H][NK]
    const float* __restrict__ eq,     // [B][NQ][H]
    const float* __restrict__ w2,
    float* __restrict__ outp)
{
    __shared__ float ex_t[G][NK];     // 8 KB, normalized softmax weights
    __shared__ float acc_s[8][G][D];  // 16 KB, per-k-partition context partials
    __shared__ float eq_s[G][H];
    __shared__ float w2_s[H];

    const int tid  = threadIdx.x;
    const int lane = tid & 63;
    const int w    = tid >> 6;
    const int b    = blockIdx.x >> 7;
    const int q0   = (blockIdx.x & 127) * G;

    if (lane < H) {
        eq_s[w][lane] = eq[((size_t)b * NQ + q0 + w) * H + lane];
        if (w == 0) w2_s[lane] = -PS * w2[lane];
    }
    __syncthreads();

    // ---- phase 1: logits (log2-domain, const term dropped) for
    //      k = 4*lane + c (l[0..3]) and k = 256 + 4*lane + c (l[4..7])
    // term = wp * rcp(1 + eqv*Ekv)  -> fma, rcp, fma: 1 trans per element.
    float l[8];
    #pragma unroll
    for (int j = 0; j < 8; ++j) l[j] = 0.f;
    const float* Ekb = Ek + (size_t)b * H * NK;
    #pragma unroll 8
    for (int h = 0; h < H; ++h) {
        const float4 v0 = reinterpret_cast<const float4*>(Ekb + h * NK)[lane];
        const float4 v1 = reinterpret_cast<const float4*>(Ekb + h * NK + 256)[lane];
        const float ev = eq_s[w][h];          // LDS broadcast
        const float wp = w2_s[h];
        l[0] = fmaf(wp, rcp_f(fmaf(ev, v0.x, 1.f)), l[0]);
        l[1] = fmaf(wp, rcp_f(fmaf(ev, v0.y, 1.f)), l[1]);
        l[2] = fmaf(wp, rcp_f(fmaf(ev, v0.z, 1.f)), l[2]);
        l[3] = fmaf(wp, rcp_f(fmaf(ev, v0.w, 1.f)), l[3]);
        l[4] = fmaf(wp, rcp_f(fmaf(ev, v1.x, 1.f)), l[4]);
        l[5] = fmaf(wp, rcp_f(fmaf(ev, v1.y, 1.f)), l[5]);
        l[6] = fmaf(wp, rcp_f(fmaf(ev, v1.z, 1.f)), l[6]);
        l[7] = fmaf(wp, rcp_f(fmaf(ev, v1.w, 1.f)), l[7]);
    }

    // ---- wave-local softmax over 512 keys (8 per lane)
    float m = l[0];
    #pragma unroll
    for (int j = 1; j < 8; ++j) m = fmaxf(m, l[j]);
    #pragma unroll
    for (int off = 32; off; off >>= 1) m = fmaxf(m, __shfl_xor(m, off));
    float e[8], s = 0.f;
    #pragma unroll
    for (int j = 0; j < 8; ++j) { e[j] = exp2_f(l[j] - m); s += e[j]; }
    #pragma unroll
    for (int off = 32; off; off >>= 1) s += __shfl_xor(s, off);
    const float inv = 1.f / s;
    const float4 st0 = { e[0] * inv, e[1] * inv, e[2] * inv, e[3] * inv };
    const float4 st1 = { e[4] * inv, e[5] * inv, e[6] * inv, e[7] * inv };
    reinterpret_cast<float4*>(&ex_t[w][0])[lane]   = st0;   // contiguous, conflict-free
    reinterpret_cast<float4*>(&ex_t[w][256])[lane] = st1;
    __syncthreads();

    // ---- phase 2: context. thread (dg, kp): 64 keys, 4 d's, 4 queries;
    //      each keys element read exactly once per block, coalesced.
    const int dg = tid & 31;
    const int kp = tid >> 5;
    const float4* k4 = reinterpret_cast<const float4*>(
        keys + ((size_t)b * NK + kp * 64) * D) + dg;
    const float4* e0p = reinterpret_cast<const float4*>(&ex_t[0][kp * 64]);
    const float4* e1p = reinterpret_cast<const float4*>(&ex_t[1][kp * 64]);
    const float4* e2p = reinterpret_cast<const float4*>(&ex_t[2][kp * 64]);
    const float4* e3p = reinterpret_cast<const float4*>(&ex_t[3][kp * 64]);
    float4 a0 = {0,0,0,0}, a1 = a0, a2 = a0, a3 = a0;
    #pragma unroll 4
    for (int kk4 = 0; kk4 < 16; ++kk4) {
        float ea[4], eb[4], ec[4], ed[4];
        *reinterpret_cast<float4*>(ea) = e0p[kk4];   // broadcast b128 reads
        *reinterpret_cast<float4*>(eb) = e1p[kk4];
        *reinterpret_cast<float4*>(ec) = e2p[kk4];
        *reinterpret_cast<float4*>(ed) = e3p[kk4];
        #pragma unroll
        for (int j = 0; j < 4; ++j) {
            float4 kv = k4[(size_t)(4 * kk4 + j) * (D / 4)];
            fma4(a0, kv, ea[j]);
            fma4(a1, kv, eb[j]);
            fma4(a2, kv, ec[j]);
            fma4(a3, kv, ed[j]);
        }
    }
    *reinterpret_cast<float4*>(&acc_s[kp][0][4 * dg]) = a0;
    *reinterpret_cast<float4*>(&acc_s[kp][1][4 * dg]) = a1;
    *reinterpret_cast<float4*>(&acc_s[kp][2][4 * dg]) = a2;
    *reinterpret_cast<float4*>(&acc_s[kp][3][4 * dg]) = a3;
    __syncthreads();

    // ---- reduce 8 partitions, write out. thread t -> float2 at flat offset 2t.
    const int o = 2 * tid;
    const int g = o >> 7;
    const int d = o & 127;
    float2 r = {0.f, 0.f};
    #pragma unroll
    for (int p = 0; p < 8; ++p) {
        float2 v = *reinterpret_cast<const float2*>(&acc_s[p][g][d]);
        r.x += v.x; r.y += v.y;
    }
    *reinterpret_cast<float2*>(&outp[((size_t)b * NQ + q0 + g) * D + d]) = r;
}

extern "C" void kernel_launch(void* const* d_in, const int* in_sizes, int n_in,
                              void* d_out, int out_size, void* d_ws, size_t ws_size,
                              hipStream_t stream) {
    const float* keys    = (const float*)d_in[0];
    const float* queries = (const float*)d_in[1];
    const float* Wk      = (const float*)d_in[2];
    const float* Wq      = (const float*)d_in[3];
    const float* b1      = (const float*)d_in[4];
    const float* w2      = (const float*)d_in[5];
    // d_in[6] = b2: dropped (softmax shift-invariant)
    float* out = (float*)d_out;

    float* Ek = (float*)d_ws;                    // B*H*NK floats (transposed)
    float* eq = Ek + (size_t)B * H * NK;         // B*NQ*H floats

    const int proj_blocks = (B * NK + B * NQ) / 8;   // 512
    proj_kernel<<<proj_blocks, 256, 0, stream>>>(keys, queries, Wk, Wq, b1, Ek, eq);
    attend_kernel<<<B * NQ / G, 256, 0, stream>>>(keys, Ek, eq, w2, out);
}

// Round 7
// 20.243 us; speedup vs baseline: 1.4910x; 1.0566x over previous
//
#include <hip/hip_runtime.h>

#define B 4
#define NQ 512
#define NK 512
#define D 128
#define H 32
#define G 4                              // queries per attend block
#define PS 2.8853900817779268f           // 2*log2(e)

__device__ __forceinline__ float rcp_f(float x)  { return __builtin_amdgcn_rcpf(x); }
__device__ __forceinline__ float exp2_f(float x) { return __builtin_amdgcn_exp2f(x); }

__device__ __forceinline__ void fma4(float4& a, const float4& v, float s) {
    a.x = fmaf(s, v.x, a.x);
    a.y = fmaf(s, v.y, a.y);
    a.z = fmaf(s, v.z, a.z);
    a.w = fmaf(s, v.w, a.w);
}

// Ek[b][h][k] = exp2(PS*(keys[b,k,:].Wk[:,h] + b1[h]))   (transposed)
// eq[b][q][h] = exp2(PS*(queries[b,q,:].Wq[:,h]))
__global__ __launch_bounds__(256) void proj_kernel(
    const float* __restrict__ keys, const float* __restrict__ queries,
    const float* __restrict__ Wk, const float* __restrict__ Wq,
    const float* __restrict__ b1,
    float* __restrict__ Ek, float* __restrict__ eq)
{
    __shared__ float xs[8][D];
    const int tid = threadIdx.x;
    const int r0 = blockIdx.x * 8;
    const bool is_q = (r0 >= B * NK);
    const float* __restrict__ X = is_q ? (queries + (size_t)(r0 - B * NK) * D)
                                       : (keys + (size_t)r0 * D);
    const float* __restrict__ W = is_q ? Wq : Wk;

    reinterpret_cast<float4*>(&xs[0][0])[tid] =
        reinterpret_cast<const float4*>(X)[tid];
    __syncthreads();

    const int lr = tid >> 5;
    const int h  = tid & 31;
    float a0 = 0.f, a1 = 0.f, a2 = 0.f, a3 = 0.f;
    const float4* x4 = reinterpret_cast<const float4*>(&xs[lr][0]);
    #pragma unroll
    for (int i = 0; i < D / 4; ++i) {
        float4 v = x4[i];
        a0 = fmaf(v.x, W[(4 * i + 0) * H + h], a0);
        a1 = fmaf(v.y, W[(4 * i + 1) * H + h], a1);
        a2 = fmaf(v.z, W[(4 * i + 2) * H + h], a2);
        a3 = fmaf(v.w, W[(4 * i + 3) * H + h], a3);
    }
    float acc = (a0 + a1) + (a2 + a3);
    if (is_q) {
        const int rq = r0 - B * NK + lr;
        eq[(size_t)rq * H + h] = exp2_f(acc * PS);
    } else {
        const int r = r0 + lr;
        const int b = r >> 9;
        const int k = r & (NK - 1);
        Ek[((size_t)b * H + h) * NK + k] = exp2_f((acc + b1[h]) * PS);
    }
}

// One block per (b, group of G=4 queries). 512 threads = 8 waves.
// Phase 1: wave pair (w, w+4) computes logits for query q0+w over k-halves
//          [0,256) and [256,512); partials combined via LDS.
// Softmax: waves 0..3 (one per query), r6's shuffle reduction.
// Phase 2: thread (dg 0..31, kp 0..15): 32 keys, 4 d's, 4 queries.
__global__ __launch_bounds__(512) void attend_kernel(
    const float* __restrict__ keys,
    const float* __restrict__ Ek,     // [B][H][NK]
    const float* __restrict__ eq,     // [B][NQ][H]
    const float* __restrict__ w2,
    float* __restrict__ outp)
{
    __shared__ float lp[8][256];       // 8 KB  logit partials per wave
    __shared__ float ex_t[G][NK];      // 8 KB  normalized softmax weights
    __shared__ float acc_s[16][G][D];  // 32 KB context partials
    __shared__ float eq_s[G][H];
    __shared__ float w2_s[H];

    const int tid  = threadIdx.x;
    const int lane = tid & 63;
    const int w    = tid >> 6;        // 0..7
    const int qw   = w & 3;           // query owned by this wave
    const int half = w >> 2;          // k-half owned by this wave
    const int b    = blockIdx.x >> 7;
    const int q0   = (blockIdx.x & 127) * G;

    if (lane < H) {
        if (w < 4)  eq_s[w][lane] = eq[((size_t)b * NQ + q0 + w) * H + lane];
        if (w == 4) w2_s[lane] = -PS * w2[lane];
    }
    __syncthreads();

    // ---- phase 1: 4 chains/lane, k = half*256 + 4*lane + c
    // term = wp * rcp(1 + eqv*Ekv): 1 trans per element.
    float l0 = 0.f, l1 = 0.f, l2 = 0.f, l3 = 0.f;
    const float* Ekb = Ek + (size_t)b * H * NK + half * 256;
    #pragma unroll 8
    for (int h = 0; h < H; ++h) {
        const float4 v = reinterpret_cast<const float4*>(Ekb + h * NK)[lane];
        const float ev = eq_s[qw][h];         // LDS broadcast
        const float wp = w2_s[h];
        l0 = fmaf(wp, rcp_f(fmaf(ev, v.x, 1.f)), l0);
        l1 = fmaf(wp, rcp_f(fmaf(ev, v.y, 1.f)), l1);
        l2 = fmaf(wp, rcp_f(fmaf(ev, v.z, 1.f)), l2);
        l3 = fmaf(wp, rcp_f(fmaf(ev, v.w, 1.f)), l3);
    }
    {
        const float4 st = { l0, l1, l2, l3 };
        reinterpret_cast<float4*>(&lp[w][0])[lane] = st;   // contiguous per wave
    }
    __syncthreads();

    // ---- softmax (waves 0..3): query w, 8 logits per lane from both halves
    if (w < 4) {
        float l[8];
        {
            const float4 L0 = reinterpret_cast<const float4*>(&lp[w][0])[lane];
            const float4 L1 = reinterpret_cast<const float4*>(&lp[w + 4][0])[lane];
            l[0] = L0.x; l[1] = L0.y; l[2] = L0.z; l[3] = L0.w;
            l[4] = L1.x; l[5] = L1.y; l[6] = L1.z; l[7] = L1.w;
        }
        float m = l[0];
        #pragma unroll
        for (int j = 1; j < 8; ++j) m = fmaxf(m, l[j]);
        #pragma unroll
        for (int off = 32; off; off >>= 1) m = fmaxf(m, __shfl_xor(m, off));
        float e[8], s = 0.f;
        #pragma unroll
        for (int j = 0; j < 8; ++j) { e[j] = exp2_f(l[j] - m); s += e[j]; }
        #pragma unroll
        for (int off = 32; off; off >>= 1) s += __shfl_xor(s, off);
        const float inv = 1.f / s;
        const float4 st0 = { e[0] * inv, e[1] * inv, e[2] * inv, e[3] * inv };
        const float4 st1 = { e[4] * inv, e[5] * inv, e[6] * inv, e[7] * inv };
        reinterpret_cast<float4*>(&ex_t[w][0])[lane]   = st0;
        reinterpret_cast<float4*>(&ex_t[w][256])[lane] = st1;
    }
    __syncthreads();

    // ---- phase 2: context. thread (dg, kp): 32 keys, 4 d's, 4 queries;
    //      each keys element read exactly once per block, coalesced.
    const int dg = tid & 31;
    const int kp = tid >> 5;          // 0..15
    const float4* k4 = reinterpret_cast<const float4*>(
        keys + ((size_t)b * NK + kp * 32) * D) + dg;
    const float4* e0p = reinterpret_cast<const float4*>(&ex_t[0][kp * 32]);
    const float4* e1p = reinterpret_cast<const float4*>(&ex_t[1][kp * 32]);
    const float4* e2p = reinterpret_cast<const float4*>(&ex_t[2][kp * 32]);
    const float4* e3p = reinterpret_cast<const float4*>(&ex_t[3][kp * 32]);
    float4 a0 = {0,0,0,0}, a1 = a0, a2 = a0, a3 = a0;
    #pragma unroll 2
    for (int kk4 = 0; kk4 < 8; ++kk4) {
        float ea[4], eb[4], ec[4], ed[4];
        *reinterpret_cast<float4*>(ea) = e0p[kk4];   // broadcast b128 reads
        *reinterpret_cast<float4*>(eb) = e1p[kk4];
        *reinterpret_cast<float4*>(ec) = e2p[kk4];
        *reinterpret_cast<float4*>(ed) = e3p[kk4];
        #pragma unroll
        for (int j = 0; j < 4; ++j) {
            float4 kv = k4[(size_t)(4 * kk4 + j) * (D / 4)];
            fma4(a0, kv, ea[j]);
            fma4(a1, kv, eb[j]);
            fma4(a2, kv, ec[j]);
            fma4(a3, kv, ed[j]);
        }
    }
    *reinterpret_cast<float4*>(&acc_s[kp][0][4 * dg]) = a0;
    *reinterpret_cast<float4*>(&acc_s[kp][1][4 * dg]) = a1;
    *reinterpret_cast<float4*>(&acc_s[kp][2][4 * dg]) = a2;
    *reinterpret_cast<float4*>(&acc_s[kp][3][4 * dg]) = a3;
    __syncthreads();

    // ---- reduce 16 partitions, write out. thread t -> (g, d).
    const int g = tid >> 7;
    const int d = tid & 127;
    float r = 0.f;
    #pragma unroll
    for (int p = 0; p < 16; ++p) r += acc_s[p][g][d];
    outp[((size_t)b * NQ + q0 + g) * D + d] = r;
}

extern "C" void kernel_launch(void* const* d_in, const int* in_sizes, int n_in,
                              void* d_out, int out_size, void* d_ws, size_t ws_size,
                              hipStream_t stream) {
    const float* keys    = (const float*)d_in[0];
    const float* queries = (const float*)d_in[1];
    const float* Wk      = (const float*)d_in[2];
    const float* Wq      = (const float*)d_in[3];
    const float* b1      = (const float*)d_in[4];
    const float* w2      = (const float*)d_in[5];
    // d_in[6] = b2: dropped (softmax shift-invariant)
    float* out = (float*)d_out;

    float* Ek = (float*)d_ws;                    // B*H*NK floats (transposed)
    float* eq = Ek + (size_t)B * H * NK;         // B*NQ*H floats

    const int proj_blocks = (B * NK + B * NQ) / 8;   // 512
    proj_kernel<<<proj_blocks, 256, 0, stream>>>(keys, queries, Wk, Wq, b1, Ek, eq);
    attend_kernel<<<B * NQ / G, 512, 0, stream>>>(keys, Ek, eq, w2, out);
}

// Round 8
// 20.129 us; speedup vs baseline: 1.4994x; 1.0056x over previous
//
#include <hip/hip_runtime.h>

#define B 4
#define NQ 512
#define NK 512
#define D 128
#define H 32
#define G 8                              // queries per attend block
#define PS 2.8853900817779268f           // 2*log2(e)

typedef float f32x2 __attribute__((ext_vector_type(2)));

__device__ __forceinline__ float rcp_f(float x)  { return __builtin_amdgcn_rcpf(x); }
__device__ __forceinline__ float exp2_f(float x) { return __builtin_amdgcn_exp2f(x); }

// packed fp32 fma: d = a*b + c elementwise on both halves (CDNA v_pk_fma_f32)
__device__ __forceinline__ f32x2 pk_fma(f32x2 a, f32x2 b, f32x2 c) {
    f32x2 d;
    asm("v_pk_fma_f32 %0, %1, %2, %3" : "=v"(d) : "v"(a), "v"(b), "v"(c));
    return d;
}

__device__ __forceinline__ void fma4(float4& a, const float4& v, float s) {
    a.x = fmaf(s, v.x, a.x);
    a.y = fmaf(s, v.y, a.y);
    a.z = fmaf(s, v.z, a.z);
    a.w = fmaf(s, v.w, a.w);
}

// Ek[b][h][k] = exp2(PS*(keys[b,k,:].Wk[:,h] + b1[h]))   (transposed)
// eq[b][q][h] = exp2(PS*(queries[b,q,:].Wq[:,h]))
__global__ __launch_bounds__(256) void proj_kernel(
    const float* __restrict__ keys, const float* __restrict__ queries,
    const float* __restrict__ Wk, const float* __restrict__ Wq,
    const float* __restrict__ b1,
    float* __restrict__ Ek, float* __restrict__ eq)
{
    __shared__ float xs[8][D];
    const int tid = threadIdx.x;
    const int r0 = blockIdx.x * 8;
    const bool is_q = (r0 >= B * NK);
    const float* __restrict__ X = is_q ? (queries + (size_t)(r0 - B * NK) * D)
                                       : (keys + (size_t)r0 * D);
    const float* __restrict__ W = is_q ? Wq : Wk;

    reinterpret_cast<float4*>(&xs[0][0])[tid] =
        reinterpret_cast<const float4*>(X)[tid];
    __syncthreads();

    const int lr = tid >> 5;
    const int h  = tid & 31;
    float a0 = 0.f, a1 = 0.f, a2 = 0.f, a3 = 0.f;
    const float4* x4 = reinterpret_cast<const float4*>(&xs[lr][0]);
    #pragma unroll
    for (int i = 0; i < D / 4; ++i) {
        float4 v = x4[i];
        a0 = fmaf(v.x, W[(4 * i + 0) * H + h], a0);
        a1 = fmaf(v.y, W[(4 * i + 1) * H + h], a1);
        a2 = fmaf(v.z, W[(4 * i + 2) * H + h], a2);
        a3 = fmaf(v.w, W[(4 * i + 3) * H + h], a3);
    }
    float acc = (a0 + a1) + (a2 + a3);
    if (is_q) {
        const int rq = r0 - B * NK + lr;
        eq[(size_t)rq * H + h] = exp2_f(acc * PS);
    } else {
        const int r = r0 + lr;
        const int b = r >> 9;
        const int k = r & (NK - 1);
        Ek[((size_t)b * H + h) * NK + k] = exp2_f((acc + b1[h]) * PS);
    }
}

// One block per (b, group of G=8 queries). 512 threads = 8 waves, wave w owns query q0+w.
// Ek[b] slab (64 KB) staged in LDS once; phase-2 acc aliases the slab region.
// Dynamic LDS: 16384 (slab/acc) + 4096 (ex) + 1024 (eqw) floats = 84 KB.
__global__ __launch_bounds__(512) void attend_kernel(
    const float* __restrict__ keys,
    const float* __restrict__ Ek,     // [B][H][NK]
    const float* __restrict__ eq,     // [B][NQ][H]
    const float* __restrict__ w2,
    float* __restrict__ outp)
{
    extern __shared__ float smem[];
    float* slab = smem;                       // [H][NK] (ph1) / acc[16][G][D] (ph2)
    float* exw  = smem + H * NK;              // [G][NK] normalized weights
    float* eqw  = smem + H * NK + G * NK;     // [G][H] float4 (ev,ev,wp,wp)

    const int tid  = threadIdx.x;
    const int lane = tid & 63;
    const int w    = tid >> 6;        // wave id == query index in group
    const int b    = blockIdx.x >> 6;
    const int q0   = (blockIdx.x & 63) * G;

    // ---- stage Ek[b] (64 KB) into LDS, coalesced
    {
        const float4* src = reinterpret_cast<const float4*>(Ek + (size_t)b * H * NK);
        float4* dst = reinterpret_cast<float4*>(slab);
        #pragma unroll
        for (int i = 0; i < 8; ++i)
            dst[tid + 512 * i] = src[tid + 512 * i];
    }
    // ---- packed per-(q,h) uniforms
    if (tid < G * H) {
        const int g = tid >> 5, h = tid & 31;
        const float ev = eq[((size_t)b * NQ + q0 + g) * H + h];
        const float wp = -PS * w2[h];
        reinterpret_cast<float4*>(eqw)[tid] = float4{ev, ev, wp, wp};
    }
    __syncthreads();

    // ---- phase 1: logits for k = 4*lane+c (acc[0..1]) and 256+4*lane+c (acc[2..3])
    // term = wp * rcp(1 + ev*Ekv): pk_fma + 2 rcp + pk_fma per pair.
    f32x2 acc0 = {0.f, 0.f}, acc1 = acc0, acc2 = acc0, acc3 = acc0;
    const f32x2 one2 = {1.f, 1.f};
    const float4* eqw4 = reinterpret_cast<const float4*>(eqw) + w * H;
    #pragma unroll 4
    for (int h = 0; h < H; ++h) {
        const float4 ew = eqw4[h];            // broadcast b128
        const f32x2 ev2 = {ew.x, ew.y};
        const f32x2 wp2 = {ew.z, ew.w};
        const float4 v0 = reinterpret_cast<const float4*>(slab + h * NK)[lane];
        const float4 v1 = reinterpret_cast<const float4*>(slab + h * NK + 256)[lane];
        f32x2 u;
        u = pk_fma(ev2, f32x2{v0.x, v0.y}, one2);
        u.x = rcp_f(u.x); u.y = rcp_f(u.y);
        acc0 = pk_fma(wp2, u, acc0);
        u = pk_fma(ev2, f32x2{v0.z, v0.w}, one2);
        u.x = rcp_f(u.x); u.y = rcp_f(u.y);
        acc1 = pk_fma(wp2, u, acc1);
        u = pk_fma(ev2, f32x2{v1.x, v1.y}, one2);
        u.x = rcp_f(u.x); u.y = rcp_f(u.y);
        acc2 = pk_fma(wp2, u, acc2);
        u = pk_fma(ev2, f32x2{v1.z, v1.w}, one2);
        u.x = rcp_f(u.x); u.y = rcp_f(u.y);
        acc3 = pk_fma(wp2, u, acc3);
    }

    // ---- softmax (per wave, no max pass: |logit*2log2e| <= 2log2e*sum|w2| ~ 16.3, fp32-safe)
    float e[8];
    e[0] = exp2_f(acc0.x); e[1] = exp2_f(acc0.y);
    e[2] = exp2_f(acc1.x); e[3] = exp2_f(acc1.y);
    e[4] = exp2_f(acc2.x); e[5] = exp2_f(acc2.y);
    e[6] = exp2_f(acc3.x); e[7] = exp2_f(acc3.y);
    float s = ((e[0] + e[1]) + (e[2] + e[3])) + ((e[4] + e[5]) + (e[6] + e[7]));
    #pragma unroll
    for (int off = 32; off; off >>= 1) s += __shfl_xor(s, off);
    const float inv = 1.f / s;
    reinterpret_cast<float4*>(exw + w * NK)[lane] =
        float4{e[0] * inv, e[1] * inv, e[2] * inv, e[3] * inv};
    reinterpret_cast<float4*>(exw + w * NK + 256)[lane] =
        float4{e[4] * inv, e[5] * inv, e[6] * inv, e[7] * inv};
    __syncthreads();                  // slab reads done -> acc may alias

    // ---- phase 2: context. thread (dg 0..31, kp 0..15): 32 keys, 4 d's, 8 queries;
    //      keys element read exactly once per block (amortized over 8 queries).
    const int dg = tid & 31;
    const int kp = tid >> 5;
    const float4* k4 = reinterpret_cast<const float4*>(
        keys + ((size_t)b * NK + kp * 32) * D) + dg;
    float4 a0 = {0,0,0,0}, a1 = a0, a2 = a0, a3 = a0, a4 = a0, a5 = a0, a6 = a0, a7 = a0;
    #pragma unroll 2
    for (int kk4 = 0; kk4 < 8; ++kk4) {
        float4 eg0, eg1, eg2, eg3, eg4, eg5, eg6, eg7;
        eg0 = reinterpret_cast<const float4*>(exw + 0 * NK + kp * 32)[kk4];
        eg1 = reinterpret_cast<const float4*>(exw + 1 * NK + kp * 32)[kk4];
        eg2 = reinterpret_cast<const float4*>(exw + 2 * NK + kp * 32)[kk4];
        eg3 = reinterpret_cast<const float4*>(exw + 3 * NK + kp * 32)[kk4];
        eg4 = reinterpret_cast<const float4*>(exw + 4 * NK + kp * 32)[kk4];
        eg5 = reinterpret_cast<const float4*>(exw + 5 * NK + kp * 32)[kk4];
        eg6 = reinterpret_cast<const float4*>(exw + 6 * NK + kp * 32)[kk4];
        eg7 = reinterpret_cast<const float4*>(exw + 7 * NK + kp * 32)[kk4];
        #pragma unroll
        for (int j = 0; j < 4; ++j) {
            const float4 kv = k4[(size_t)(4 * kk4 + j) * (D / 4)];
            const float s0 = j == 0 ? eg0.x : j == 1 ? eg0.y : j == 2 ? eg0.z : eg0.w;
            const float s1 = j == 0 ? eg1.x : j == 1 ? eg1.y : j == 2 ? eg1.z : eg1.w;
            const float s2 = j == 0 ? eg2.x : j == 1 ? eg2.y : j == 2 ? eg2.z : eg2.w;
            const float s3 = j == 0 ? eg3.x : j == 1 ? eg3.y : j == 2 ? eg3.z : eg3.w;
            const float s4 = j == 0 ? eg4.x : j == 1 ? eg4.y : j == 2 ? eg4.z : eg4.w;
            const float s5 = j == 0 ? eg5.x : j == 1 ? eg5.y : j == 2 ? eg5.z : eg5.w;
            const float s6 = j == 0 ? eg6.x : j == 1 ? eg6.y : j == 2 ? eg6.z : eg6.w;
            const float s7 = j == 0 ? eg7.x : j == 1 ? eg7.y : j == 2 ? eg7.z : eg7.w;
            fma4(a0, kv, s0); fma4(a1, kv, s1); fma4(a2, kv, s2); fma4(a3, kv, s3);
            fma4(a4, kv, s4); fma4(a5, kv, s5); fma4(a6, kv, s6); fma4(a7, kv, s7);
        }
    }
    {
        float* accm = slab;           // [16][G][D] aliases the staged slab
        const int base = (kp * G) * D + 4 * dg;
        *reinterpret_cast<float4*>(accm + base + 0 * D) = a0;
        *reinterpret_cast<float4*>(accm + base + 1 * D) = a1;
        *reinterpret_cast<float4*>(accm + base + 2 * D) = a2;
        *reinterpret_cast<float4*>(accm + base + 3 * D) = a3;
        *reinterpret_cast<float4*>(accm + base + 4 * D) = a4;
        *reinterpret_cast<float4*>(accm + base + 5 * D) = a5;
        *reinterpret_cast<float4*>(accm + base + 6 * D) = a6;
        *reinterpret_cast<float4*>(accm + base + 7 * D) = a7;
    }
    __syncthreads();

    // ---- reduce 16 partitions; thread t -> outputs t and t+512 over (g,d)
    const float* accm = slab;
    #pragma unroll
    for (int r0 = 0; r0 < 2; ++r0) {
        const int o = tid + r0 * 512;
        const int g = o >> 7;
        const int d = o & 127;
        float r = 0.f;
        #pragma unroll
        for (int p = 0; p < 16; ++p) r += accm[(p * G + g) * D + d];
        outp[((size_t)b * NQ + q0 + g) * D + d] = r;
    }
}

extern "C" void kernel_launch(void* const* d_in, const int* in_sizes, int n_in,
                              void* d_out, int out_size, void* d_ws, size_t ws_size,
                              hipStream_t stream) {
    const float* keys    = (const float*)d_in[0];
    const float* queries = (const float*)d_in[1];
    const float* Wk      = (const float*)d_in[2];
    const float* Wq      = (const float*)d_in[3];
    const float* b1      = (const float*)d_in[4];
    const float* w2      = (const float*)d_in[5];
    // d_in[6] = b2: dropped (softmax shift-invariant)
    float* out = (float*)d_out;

    float* Ek = (float*)d_ws;                    // B*H*NK floats (transposed)
    float* eq = Ek + (size_t)B * H * NK;         // B*NQ*H floats

    const int proj_blocks = (B * NK + B * NQ) / 8;   // 512
    proj_kernel<<<proj_blocks, 256, 0, stream>>>(keys, queries, Wk, Wq, b1, Ek, eq);

    const size_t lds_bytes = (size_t)(H * NK + G * NK + G * H * 4) * sizeof(float); // 84 KB
    attend_kernel<<<B * NQ / G, 512, lds_bytes, stream>>>(keys, Ek, eq, w2, out);
}